// Round 1
// baseline (1536.361 us; speedup 1.0000x reference)
//
#include <hip/hip_runtime.h>
#include <cstdint>
#include <cstddef>

#define BATCH   32768
#define DIM     768
#define POOL    20
#define TOPK    9

// ws layout:
//   [0,      61440)  kn      float[20*768]   (normalized keys[layer])
//   [61440,  61520)  cnt     int[20]         (global top-k index histogram)
//   [61568,  61728)  rowsum  double[20]      (sum over pools of sim row r, r<20)

__global__ __launch_bounds__(256) void prep_kernel(
    const float* __restrict__ keys, const int* __restrict__ layerp,
    float* __restrict__ kn, int* __restrict__ cnt)
{
    const int layer = *layerp;
    const int tid  = threadIdx.x;
    const int lane = tid & 63;
    const int wid  = tid >> 6;
    if (tid < POOL) cnt[tid] = 0;
    for (int r = wid; r < POOL; r += 4) {
        const float* krow = keys + ((size_t)layer * POOL + r) * DIM;
        float v[12];
        double ss = 0.0;
#pragma unroll
        for (int j = 0; j < 12; ++j) {
            v[j] = krow[lane + 64 * j];
            ss += (double)v[j] * (double)v[j];
        }
#pragma unroll
        for (int off = 32; off >= 1; off >>= 1) ss += __shfl_xor(ss, off);
        float n = fmaxf((float)sqrt(ss), 1e-12f);
#pragma unroll
        for (int j = 0; j < 12; ++j)
            kn[(size_t)r * DIM + lane + 64 * j] = v[j] / n;
    }
}

__global__ __launch_bounds__(256) void pool_main(
    const float* __restrict__ x, const float* __restrict__ prompts,
    const int* __restrict__ layerp, const float* __restrict__ kn,
    float* __restrict__ out, int* __restrict__ cnt, double* __restrict__ rowsum)
{
    __shared__ float4 knlds4[POOL * DIM / 4];   // 61440 B
    __shared__ int    hcnt[POOL];

    const int tid  = threadIdx.x;
    const int lane = tid & 63;
    const int wid  = tid >> 6;

    if (tid < POOL) hcnt[tid] = 0;
    const float4* kn4 = (const float4*)kn;
    for (int i = tid; i < POOL * DIM / 4; i += 256) knlds4[i] = kn4[i];
    __syncthreads();

    const float* knl   = (const float*)knlds4;
    const int    layer = *layerp;
    const float* pl    = prompts + (size_t)layer * POOL * DIM;  // LEN_PROMPTS == 1

    const int gw = blockIdx.x * 4 + wid;   // 0..2047 global wave id

    for (int r = 0; r < 16; ++r) {
        const int row = gw * 16 + r;

        // ---- load x row: lane holds 12 contiguous floats at offset lane*12 ----
        const float4* xr = (const float4*)(x + (size_t)row * DIM + lane * 12);
        float xv[12];
        {
            float4 a = xr[0], b = xr[1], c = xr[2];
            xv[0]=a.x; xv[1]=a.y; xv[2]=a.z;  xv[3]=a.w;
            xv[4]=b.x; xv[5]=b.y; xv[6]=b.z;  xv[7]=b.w;
            xv[8]=c.x; xv[9]=c.y; xv[10]=c.z; xv[11]=c.w;
        }

        // ---- L2 norm of x row (double accumulate, butterfly reduce) ----
        double ss = 0.0;
#pragma unroll
        for (int j = 0; j < 12; ++j) ss += (double)xv[j] * (double)xv[j];
#pragma unroll
        for (int off = 32; off >= 1; off >>= 1) ss += __shfl_xor(ss, off);
        float n = fmaxf((float)sqrt(ss), 1e-12f);
#pragma unroll
        for (int j = 0; j < 12; ++j) xv[j] = xv[j] / n;   // xn, fp32 like ref

        // ---- 20 dot products: double accumulation, lane p<20 keeps sim_p ----
        double mysim = -1e300;
        double rs    = 0.0;
#pragma unroll
        for (int p = 0; p < POOL; ++p) {
            const float4* kp4 = (const float4*)(knl + p * DIM + lane * 12);
            float4 a = kp4[0], b = kp4[1], c = kp4[2];
            float kv[12];
            kv[0]=a.x; kv[1]=a.y; kv[2]=a.z;  kv[3]=a.w;
            kv[4]=b.x; kv[5]=b.y; kv[6]=b.z;  kv[7]=b.w;
            kv[8]=c.x; kv[9]=c.y; kv[10]=c.z; kv[11]=c.w;
            double s = 0.0;
#pragma unroll
            for (int j = 0; j < 12; ++j) s = fma((double)xv[j], (double)kv[j], s);
#pragma unroll
            for (int off = 32; off >= 1; off >>= 1) s += __shfl_xor(s, off);
            if (lane == p) mysim = s;
            rs += s;
        }
        if (row < POOL && lane == 0) rowsum[row] = rs;

        // ---- top-9: wave argmax, descending, ties -> lower index ----
        int sel[TOPK];
        double vv = mysim;   // lanes >= POOL hold -1e300, never win
#pragma unroll
        for (int t = 0; t < TOPK; ++t) {
            double bv = vv;
            int    bi = lane;
#pragma unroll
            for (int off = 32; off >= 1; off >>= 1) {
                double ov = __shfl_xor(bv, off);
                int    oi = __shfl_xor(bi, off);
                if (ov > bv || (ov == bv && oi < bi)) { bv = ov; bi = oi; }
            }
            sel[t] = bi;                 // uniform across wave
            if (lane == bi) vv = -1e300; // remove winner
        }

        // ---- histogram (per-lane delta -> LDS) ----
        int delta = 0;
#pragma unroll
        for (int t = 0; t < TOPK; ++t) delta += (sel[t] == lane) ? 1 : 0;
        if (delta) atomicAdd(&hcnt[lane], delta);

        // ---- gather-write 9 x 768 floats, coalesced float4 ----
        float* orow = out + (size_t)row * (TOPK * DIM);
#pragma unroll
        for (int t = 0; t < TOPK; ++t) {
            const float4* src = (const float4*)(pl + (size_t)sel[t] * DIM);
            float4*       dst = (float4*)(orow + (size_t)t * DIM);
            dst[lane]       = src[lane];
            dst[lane + 64]  = src[lane + 64];
            dst[lane + 128] = src[lane + 128];
        }
    }

    __syncthreads();
    if (tid < POOL) atomicAdd(&cnt[tid], hcnt[tid]);
}

__global__ __launch_bounds__(64) void finalize_kernel(
    const int* __restrict__ cnt, const double* __restrict__ rowsum,
    float* __restrict__ out)
{
    const int lane = threadIdx.x & 63;
    double v = (lane < POOL) ? (double)cnt[lane] * rowsum[lane] : 0.0;
#pragma unroll
    for (int off = 32; off >= 1; off >>= 1) v += __shfl_xor(v, off);
    if (lane == 0) {
        const double denom = (double)BATCH * TOPK * POOL;
        out[(size_t)BATCH * TOPK * DIM] = (float)(1.0 - v / denom);
    }
}

extern "C" void kernel_launch(void* const* d_in, const int* in_sizes, int n_in,
                              void* d_out, int out_size, void* d_ws, size_t ws_size,
                              hipStream_t stream) {
    const float* x       = (const float*)d_in[0];
    const float* keys    = (const float*)d_in[1];
    const float* prompts = (const float*)d_in[2];
    const int*   layerp  = (const int*)d_in[3];
    float* out = (float*)d_out;

    char*   ws     = (char*)d_ws;
    float*  kn     = (float*)ws;
    int*    cnt    = (int*)(ws + 61440);
    double* rowsum = (double*)(ws + 61568);

    prep_kernel<<<1, 256, 0, stream>>>(keys, layerp, kn, cnt);
    pool_main<<<512, 256, 0, stream>>>(x, prompts, layerp, kn, out, cnt, rowsum);
    finalize_kernel<<<1, 64, 0, stream>>>(cnt, rowsum, out);
}